// Round 5
// baseline (120.567 us; speedup 1.0000x reference)
//
#include <hip/hip_runtime.h>
#include <hip/hip_bf16.h>

// Problem constants (from reference)
#define N_NODES 4096
#define F_IN    128
#define UNITS   64
#define HEADS   4
#define WT_PITCH 132   // 128 + 4 pad for w-transpose LDS tile
#define CHUNK   64     // neighbor chunk for kC (expected n ~41)
#define CAP     160    // neighbor-list capacity (mean 41, sd 6.4 -> 18 sigma headroom)

// ---------------------------------------------------------------------------
// Kernel A (fused): blocks 0..255 compute x = inputs@w, e1, e2, partial column
// sums (GEMM path); blocks 256..4351 scan adjacency rows and compact neighbor
// lists into workspace (scan path). The scan is HBM-bound (67 MB); the GEMM's
// VALU/LDS work hides underneath it via co-resident waves.
// ---------------------------------------------------------------------------
__global__ __launch_bounds__(256) void kA(const float* __restrict__ inputs,
                                          const float* __restrict__ adj,
                                          const float* __restrict__ w,
                                          const float* __restrict__ aw1,
                                          const float* __restrict__ aw2,
                                          float* __restrict__ x,
                                          float* __restrict__ e1,
                                          float* __restrict__ e2,
                                          float* __restrict__ partial,
                                          int* __restrict__ cnt_ws,
                                          unsigned short* __restrict__ nbr_ws) {
    __shared__ union {
        struct {
            float w_t[UNITS * WT_PITCH];      // 33.8 KB
            float in_lds[16 * F_IN];          // 8 KB
            float x_lds[16 * 65];             // 4.2 KB
            float aw_lds[2 * UNITS * HEADS];  // 2 KB
        } g;
        struct {
            unsigned short nbr_l[CAP];
            int cnt;
        } s;
    } sm;

    const int t = threadIdx.x;

    if (blockIdx.x < 256) {
        // ---------------- GEMM path ----------------
        const int b = blockIdx.x;
        const int row0 = b * 16;

        for (int idx = t; idx < F_IN * UNITS; idx += 256) {
            const int u = idx & 63;
            const int k = idx >> 6;
            sm.g.w_t[u * WT_PITCH + k] = w[idx];
        }
        {
            const float4* src = (const float4*)(inputs + (size_t)row0 * F_IN);
            float4* dst = (float4*)sm.g.in_lds;
            for (int idx = t; idx < 16 * F_IN / 4; idx += 256) dst[idx] = src[idx];
        }
        if (t < UNITS * HEADS) {
            sm.g.aw_lds[t] = aw1[t];
            sm.g.aw_lds[UNITS * HEADS + t] = aw2[t];
        }
        __syncthreads();

        const int u = t & 63;
        const int rg = t >> 6;
        float acc0 = 0.f, acc1 = 0.f, acc2 = 0.f, acc3 = 0.f;
        const float4* wrow = (const float4*)(sm.g.w_t + u * WT_PITCH);
        const float4* i0 = (const float4*)(sm.g.in_lds + (rg * 4 + 0) * F_IN);
        const float4* i1 = (const float4*)(sm.g.in_lds + (rg * 4 + 1) * F_IN);
        const float4* i2 = (const float4*)(sm.g.in_lds + (rg * 4 + 2) * F_IN);
        const float4* i3 = (const float4*)(sm.g.in_lds + (rg * 4 + 3) * F_IN);
#pragma unroll 8
        for (int c = 0; c < F_IN / 4; c++) {
            const float4 wv = wrow[c];
            float4 v;
            v = i0[c]; acc0 = fmaf(wv.x, v.x, fmaf(wv.y, v.y, fmaf(wv.z, v.z, fmaf(wv.w, v.w, acc0))));
            v = i1[c]; acc1 = fmaf(wv.x, v.x, fmaf(wv.y, v.y, fmaf(wv.z, v.z, fmaf(wv.w, v.w, acc1))));
            v = i2[c]; acc2 = fmaf(wv.x, v.x, fmaf(wv.y, v.y, fmaf(wv.z, v.z, fmaf(wv.w, v.w, acc2))));
            v = i3[c]; acc3 = fmaf(wv.x, v.x, fmaf(wv.y, v.y, fmaf(wv.z, v.z, fmaf(wv.w, v.w, acc3))));
        }
        sm.g.x_lds[(rg * 4 + 0) * 65 + u] = acc0;
        sm.g.x_lds[(rg * 4 + 1) * 65 + u] = acc1;
        sm.g.x_lds[(rg * 4 + 2) * 65 + u] = acc2;
        sm.g.x_lds[(rg * 4 + 3) * 65 + u] = acc3;
        x[(size_t)(row0 + rg * 4 + 0) * UNITS + u] = acc0;
        x[(size_t)(row0 + rg * 4 + 1) * UNITS + u] = acc1;
        x[(size_t)(row0 + rg * 4 + 2) * UNITS + u] = acc2;
        x[(size_t)(row0 + rg * 4 + 3) * UNITS + u] = acc3;
        __syncthreads();

        if (t < 128) {
            const int r = t >> 3;
            const int rem = t & 7;
            const int h = rem & 3;
            const bool first = rem < 4;
            const float* aw = sm.g.aw_lds + (first ? 0 : UNITS * HEADS);
            float s = 0.f;
#pragma unroll 8
            for (int uu = 0; uu < UNITS; uu++)
                s += sm.g.x_lds[r * 65 + uu] * aw[uu * HEADS + h];
            (first ? e1 : e2)[(size_t)(row0 + r) * HEADS + h] = s;
        }

        if (t < 64) {
            float s = 0.f;
#pragma unroll
            for (int r = 0; r < 16; r++) s += sm.g.x_lds[r * 65 + t];
            partial[b * 64 + t] = s;
        }
    } else {
        // ---------------- scan path ----------------
        const int i = blockIdx.x - 256;
        if (t == 0) sm.s.cnt = 0;
        __syncthreads();

        const float4* arow = (const float4*)(adj + (size_t)i * N_NODES);
        const float4 v0 = arow[t];
        const float4 v1 = arow[t + 256];
        const float4 v2 = arow[t + 512];
        const float4 v3 = arow[t + 768];

#define EMIT(val, col) if ((val) != 0.f) { int _i = atomicAdd(&sm.s.cnt, 1); if (_i < CAP) sm.s.nbr_l[_i] = (unsigned short)(col); }
        {
            const int b0 = t * 4;
            EMIT(v0.x, b0 + 0) EMIT(v0.y, b0 + 1) EMIT(v0.z, b0 + 2) EMIT(v0.w, b0 + 3)
            const int b1 = (t + 256) * 4;
            EMIT(v1.x, b1 + 0) EMIT(v1.y, b1 + 1) EMIT(v1.z, b1 + 2) EMIT(v1.w, b1 + 3)
            const int b2 = (t + 512) * 4;
            EMIT(v2.x, b2 + 0) EMIT(v2.y, b2 + 1) EMIT(v2.z, b2 + 2) EMIT(v2.w, b2 + 3)
            const int b3 = (t + 768) * 4;
            EMIT(v3.x, b3 + 0) EMIT(v3.y, b3 + 1) EMIT(v3.z, b3 + 2) EMIT(v3.w, b3 + 3)
        }
#undef EMIT
        __syncthreads();

        const int m = min(sm.s.cnt, CAP);
        if (t == 0) cnt_ws[i] = m;
        if (t < m) nbr_ws[(size_t)i * CAP + t] = sm.s.nbr_l[t];
    }
}

// ---------------------------------------------------------------------------
// Kernel B: S[u] = sum over 256 block-partials (256 threads, 4-way split)
// ---------------------------------------------------------------------------
__global__ __launch_bounds__(256) void kB(const float* __restrict__ partial,
                                          float* __restrict__ S) {
    __shared__ float red[4][64];
    const int u = threadIdx.x & 63;
    const int q = threadIdx.x >> 6;
    float s = 0.f;
#pragma unroll 8
    for (int b = q; b < 256; b += 4) s += partial[b * 64 + u];
    red[q][u] = s;
    __syncthreads();
    if (threadIdx.x < 64) S[u] = red[0][u] + red[1][u] + red[2][u] + red[3][u];
}

// ---------------------------------------------------------------------------
// Kernel C: per row i — load precomputed neighbor list (no adj re-read!),
// two-phase sparse softmax-corrected aggregation.
//   phase A: compute wgt[k][h] AND stage x rows of the chunk into LDS
//   phase B: pure-LDS tight loop: 2 LDS reads + 2 FMA per neighbor
// out[i, h*64+u] = relu((S[u]+acc)/(N+den)).
// ---------------------------------------------------------------------------
__global__ __launch_bounds__(256) void kC(const float* __restrict__ x,
                                          const float* __restrict__ e1,
                                          const float* __restrict__ e2,
                                          const float* __restrict__ S,
                                          const int* __restrict__ cnt_ws,
                                          const unsigned short* __restrict__ nbr_ws,
                                          float* __restrict__ out) {
    __shared__ unsigned short nbr[CAP];       // 0.3 KB
    __shared__ float xs[CHUNK * UNITS];       // 16 KB — staged x rows for chunk
    __shared__ float wgt[CHUNK * 4];          // 1 KB

    const int i = blockIdx.x;
    const int t = threadIdx.x;

    const int n = cnt_ws[i];
    if (t < n) nbr[t] = nbr_ws[(size_t)i * CAP + t];
    __syncthreads();

    const int h = t >> 6;
    const int u = t & 63;

    const float4 e1v = *(const float4*)(e1 + (size_t)i * HEADS);

    float acc = 0.f;   // sum_k wgt[k][h] * x[j_k][u]
    float den = 0.f;   // sum_k wgt[k][h]

    for (int base = 0; base < n; base += CHUNK) {
        const int m = min(n - base, CHUNK);

        // phase A1: weights for this chunk (threads 0..m-1)
        if (t < m) {
            const int j = nbr[base + t];
            const float4 e2v = *(const float4*)(e2 + (size_t)j * HEADS);
            float4 wv;
            wv.x = __expf(fmaxf(e1v.x + e2v.x, 0.f)) - 1.f;
            wv.y = __expf(fmaxf(e1v.y + e2v.y, 0.f)) - 1.f;
            wv.z = __expf(fmaxf(e1v.z + e2v.z, 0.f)) - 1.f;
            wv.w = __expf(fmaxf(e1v.w + e2v.w, 0.f)) - 1.f;
            *(float4*)(wgt + t * 4) = wv;
        }
        // phase A2: stage x rows of the chunk (coalesced: 64 lanes = one row)
        for (int idx = t; idx < m * UNITS; idx += 256) {
            const int k = idx >> 6;
            const int uu = idx & 63;
            xs[idx] = x[(size_t)nbr[base + k] * UNITS + uu];
        }
        __syncthreads();

        // phase B: pure-LDS tight loop
#pragma unroll 8
        for (int k = 0; k < m; k++) {
            const float wv = wgt[k * 4 + h];        // LDS broadcast (h wave-uniform)
            den += wv;
            acc = fmaf(wv, xs[k * UNITS + u], acc); // conflict-free (2-way, free)
        }
        __syncthreads();   // protect wgt/xs before next chunk overwrites
    }

    const float numer = S[u] + acc;
    const float denom = (float)N_NODES + den;
    out[(size_t)i * (HEADS * UNITS) + t] = fmaxf(numer / denom, 0.f);
}

// ---------------------------------------------------------------------------
extern "C" void kernel_launch(void* const* d_in, const int* in_sizes, int n_in,
                              void* d_out, int out_size, void* d_ws, size_t ws_size,
                              hipStream_t stream) {
    const float* inputs = (const float*)d_in[0];
    const float* adj    = (const float*)d_in[1];
    const float* w      = (const float*)d_in[2];
    const float* aw1    = (const float*)d_in[3];
    const float* aw2    = (const float*)d_in[4];
    float* out = (float*)d_out;

    // workspace layout:
    // floats: x[262144] | e1[16384] | e2[16384] | partial[16384] | S[64]
    // then:   cnt_ws[4096] (int) | nbr_ws[4096*CAP] (ushort)
    float* ws = (float*)d_ws;
    float* x       = ws;
    float* e1      = ws + 262144;
    float* e2      = ws + 262144 + 16384;
    float* partial = ws + 262144 + 2 * 16384;
    float* S       = ws + 262144 + 3 * 16384;
    int* cnt_ws    = (int*)(S + 64);
    unsigned short* nbr_ws = (unsigned short*)(cnt_ws + N_NODES);

    kA<<<256 + N_NODES, 256, 0, stream>>>(inputs, adj, w, aw1, aw2,
                                          x, e1, e2, partial, cnt_ws, nbr_ws);
    kB<<<1, 256, 0, stream>>>(partial, S);
    kC<<<N_NODES, 256, 0, stream>>>(x, e1, e2, S, cnt_ws, nbr_ws, out);
}